// Round 1
// baseline (37.146 us; speedup 1.0000x reference)
//
#include <hip/hip_runtime.h>

// Problem constants (from reference):
//   x: [B=512, C=64, T=640] f32
//   channel_idx: 64 int32 indices into [0, 110)
//   out: [B, 110, T] f32 (reshaped to [B,10,11,T] by harness — same flat layout)
#define BATCH 512
#define N_CH 64
#define T_LEN 640
#define GRID_CELLS 110
#define T4 (T_LEN / 4)                      // 160 float4 per row
#define TOTAL4 (BATCH * GRID_CELLS * T4)    // 9,011,200 float4 output elems

__global__ __launch_bounds__(256) void spatial_scatter_kernel(
    const float4* __restrict__ x,          // [B, C, T4]
    const int* __restrict__ channel_idx,   // [C]
    float4* __restrict__ out)              // [B, 110, T4]
{
    __shared__ int inv[GRID_CELLS];        // grid cell -> source channel or -1
    const int tid = threadIdx.x;
    if (tid < GRID_CELLS) inv[tid] = -1;
    __syncthreads();
    if (tid < N_CH) inv[channel_idx[tid]] = tid;
    __syncthreads();

    const float4 zero = make_float4(0.f, 0.f, 0.f, 0.f);
    const int stride = gridDim.x * blockDim.x;
    for (int i = blockIdx.x * blockDim.x + tid; i < TOTAL4; i += stride) {
        const int t4 = i % T4;             // const divisors -> magic-mul, cheap
        const int bg = i / T4;
        const int g  = bg % GRID_CELLS;
        const int b  = bg / GRID_CELLS;
        const int c  = inv[g];             // broadcast within wave (same row)
        float4 v = zero;
        if (c >= 0) {
            v = x[(b * N_CH + c) * T4 + t4];
        }
        out[i] = v;
    }
}

extern "C" void kernel_launch(void* const* d_in, const int* in_sizes, int n_in,
                              void* d_out, int out_size, void* d_ws, size_t ws_size,
                              hipStream_t stream) {
    const float4* x = (const float4*)d_in[0];
    const int* channel_idx = (const int*)d_in[1];
    float4* out = (float4*)d_out;

    // Memory-bound: cap grid and grid-stride (Guideline 11).
    const int block = 256;
    int blocks = (TOTAL4 + block - 1) / block;
    if (blocks > 2048) blocks = 2048;
    spatial_scatter_kernel<<<blocks, block, 0, stream>>>(x, channel_idx, out);
}